// Round 10
// baseline (176.795 us; speedup 1.0000x reference)
//
#include <hip/hip_runtime.h>
#include <hip/hip_bf16.h>

#define HW 9216          // 96*96
#define NPC 18432        // per-channel element count for BN
#define NELEM 1179648    // 2*64*96*96
#define XSTR 72          // patch x stride (bf16): %8==0, 36dw = +4 banks/pos
#define PATCH_B 7776     // 3*18*72*2 bytes
#define XREC 12          // cross-wave exchange record: 12 f32 = 48 B (16B-aligned)
#define XBUF_B (4*2*16*2*XREC*4)   // 4 slots x o2 x pos x g x rec = 12288 B

typedef __attribute__((ext_vector_type(2))) float f32x2;
typedef __attribute__((ext_vector_type(4))) float f32x4v;
typedef __attribute__((ext_vector_type(8))) short short8v;   // 8 bf16 (4 VGPRs)

__device__ __forceinline__ int detect_is32(const unsigned short* __restrict__ w1u) {
    int lane = threadIdx.x & 63;
    int bad = 0;
    #pragma unroll
    for (int i = 0; i < 16; ++i) {
        unsigned short u = (unsigned short)(w1u[lane + i * 64] & 0x7FFF);
        bad |= (u >= 0x42C8);   // bf16 |v| >= 100 or NaN/Inf
    }
    return (__ballot(bad) != 0ULL) ? 1 : 0;
}

__device__ __forceinline__ float load_in(const void* p, int idx, int is32) {
    return is32 ? ((const float*)p)[idx]
                : __bfloat162float(((const __hip_bfloat16*)p)[idx]);
}

__device__ __forceinline__ float lo16(unsigned v) { return __int_as_float((int)(v << 16)); }
__device__ __forceinline__ float hi16(unsigned v) { return __int_as_float((int)(v & 0xFFFF0000u)); }
__device__ __forceinline__ unsigned pk2bf(float a, float b) {
    __hip_bfloat162 h = __float22bfloat162_rn(float2{a, b});
    return *(unsigned*)&h;
}

__device__ __forceinline__ float dotsq4(const f32x4v a) {
    float t = a[0] * a[0];
    t = fmaf(a[1], a[1], t);
    t = fmaf(a[2], a[2], t);
    t = fmaf(a[3], a[3], t);
    return t;
}

// ---------------------------------------------------------------------------
// prep: 0..575 x-transpose to bf16 [b][y][x][c]; 576..719 MFMA B-fragment
// tables; 720 zero BN-stat accumulators.
// R26 full-chain A-row remap: A-row R (= lane&15) of fragment (o,k,g,h)
// stores chain i_local(R) = 2*((R>>2)&1) + (R>>3) at m = 4h + (R&3), active
// k-chunk (lane>>4) == i_local. Then D-lane quad q (rows 4q..4q+3) receives
// its OWN chain i = g*4 + 2*(q&1) + (q>>1), m-half h. After both h-calls a
// lane holds its full 8-dim chain -> phase-2 k-loop needs ZERO shuffles
// (dot8/n1/acc all in-lane). Pure table relabel, same slots/addressing.
// ---------------------------------------------------------------------------
__launch_bounds__(256)
__global__ void prep_kernel(const void* __restrict__ x,
                            const void* __restrict__ w1, const void* __restrict__ w2,
                            __hip_bfloat16* __restrict__ xt,
                            __hip_bfloat16* __restrict__ Bfr1,
                            __hip_bfloat16* __restrict__ Bfr2,
                            float* __restrict__ statz) {
    __shared__ float tile[64 * 33];
    const int bid = blockIdx.x;
    if (bid < 576) {
        const int is32 = detect_is32((const unsigned short*)w1);
        int xb = bid % 3, y = (bid / 3) % 96, b = bid / 288;
        int x0 = xb * 32;
        for (int e = threadIdx.x; e < 2048; e += 256) {
            int xl = e & 31, c = e >> 5;
            tile[c * 33 + xl] = load_in(x, ((b * 64 + c) * 96 + y) * 96 + x0 + xl, is32);
        }
        __syncthreads();
        for (int f = threadIdx.x; f < 1024; f += 256) {
            int c2 = f & 31, xl = f >> 5;
            float a = tile[(2 * c2) * 33 + xl];
            float c = tile[(2 * c2 + 1) * 33 + xl];
            *(unsigned*)&xt[((b * 96 + y) * 96 + x0 + xl) * 64 + 2 * c2] = pk2bf(a, c);
        }
    } else if (bid < 720) {
        const int is32 = detect_is32((const unsigned short*)w1);
        int t = (bid - 576) * 256 + threadIdx.x;   // 0..36863
        int layer = t / 18432;
        int r = t - layer * 18432;
        int lane = r & 63;
        int fi = r >> 6;                 // 0..287 = ((o*9+k)*2+g)*2+h
        int h = fi & 1, g = (fi >> 1) & 1;
        int kq = fi >> 2;
        int k = kq % 9, o = kq / 9;
        int dy = k / 3, dx = k % 3;
        int quadA = lane >> 4;           // k-chunk of the A operand
        int row = lane & 15;             // A-row = D-row
        int qD = row >> 2;               // D-quad that receives this row
        int il = 2 * (qD & 1) + (qD >> 1);   // own chain of lane quad qD
        int act = (quadA == il);
        int i = g * 4 + il;
        int m = 4 * h + (row & 3);
        const void* w = layer ? w2 : w1;
        __hip_bfloat16* dst = layer ? Bfr2 : Bfr1;
        #pragma unroll
        for (int j = 0; j < 8; ++j) {
            float v = act ? load_in(w, ((((o * 8 + i) * 3 + dy) * 3 + dx) * 8 + j) * 8 + m, is32)
                          : 0.f;
            dst[(fi * 64 + lane) * 8 + j] = __float2bfloat16(v);
        }
    } else {
        for (int e = threadIdx.x; e < 2048; e += 256) statz[e] = 0.f;
    }
}

// cross-wave (g) exchange of 8-float partial + se through a 48B LDS record.
// All quads hold identical post-xor16/xor32 values; quad 0 writes.
__device__ __forceinline__ void xexchange8(float* __restrict__ xbufF, int slot,
                                           int o2w, int pos16, int g, int quad,
                                           float ac[8], float& se) {
    float* rec = xbufF + ((((slot * 2 + o2w) * 16 + pos16) * 2 + g) * XREC);
    if (quad == 0) {
        *(float4*)(rec)     = make_float4(ac[0], ac[1], ac[2], ac[3]);
        *(float4*)(rec + 4) = make_float4(ac[4], ac[5], ac[6], ac[7]);
        rec[8] = se;
    }
    __syncthreads();
    const float* prec = xbufF + ((((slot * 2 + o2w) * 16 + pos16) * 2 + (1 - g)) * XREC);
    float4 pa = *(const float4*)(prec);
    float4 pb = *(const float4*)(prec + 4);
    ac[0] += pa.x; ac[1] += pa.y; ac[2] += pa.z; ac[3] += pa.w;
    ac[4] += pb.x; ac[5] += pb.y; ac[6] += pb.z; ac[7] += pb.w;
    se += prec[8];
}

// ---------------------------------------------------------------------------
// Fused capsule conv (MFMA) + routing + BN-stat partials.  (R26 = R25 +
// full-chain A-row remap: every lane holds its own chain's full 8-dim
// prior vector -> the 3x9 exp loop is PURE VALU, no DS on critical path.)
// R25 measured: caps 52.6us, VALUBusy 62% — 54 per-k DS-shuffles on the
// dp->shfl->exp->shfl->acc chain were the stall source. Now:
//   n1o[k] = in-lane dotsq8; d = in-lane dot8(P,om8); ac8 += e*P in-lane.
//   Reductions once per iteration: se (xor16+xor32), ac8 (8x xor16 +
//   8x xor32), one 9-float g-exchange + barrier. om8/n2 fully in-lane.
// Cost: +8 working VGPRs (om8, ac8) — combined ~144, stays 3 waves/SIMD.
// Block = 256 threads = 4 waves; tile = 16 x-positions x TWO o.
// Wave wv = (o2w = wv>>1, g = wv&1); lane quad q = (ihl = q>>1, mhalf = q&1);
// own chain i = g*4 + 2*mhalf + ihl.
// ---------------------------------------------------------------------------
__launch_bounds__(256, 4)
__global__ void caps_kernel(const __hip_bfloat16* __restrict__ in,  // [b][y][x][64] bf16
                            const float* __restrict__ statPrev,     // BN1 raw stats (layer2)
                            const void* __restrict__ gamma, const void* __restrict__ beta,
                            const void* __restrict__ wdt,           // w1, dtype probe
                            const __hip_bfloat16* __restrict__ Bfr,
                            __hip_bfloat16* __restrict__ yout,      // [b][y][x][64] bf16
                            float* __restrict__ statL,              // [8 copies][128]
                            int layer1) {
    __shared__ __align__(16) unsigned char smem[PATCH_B + XBUF_B];
    __hip_bfloat16* patchH = (__hip_bfloat16*)smem;       // [q=row*18+xo][c] stride XSTR
    float* xbufF = (float*)(smem + PATCH_B);              // exchange slots
    float* omF = (float*)smem;                // 1 KB, aliases patch (dead in epilogue)
    float* scL = (float*)(smem + PATCH_B);    // 256 B, aliases xbuf (staging only)
    float* shL = scL + 64;

    const int gx    = blockIdx.x;    // 0..23
    const int opair = gx & 3;
    const int x0    = (gx >> 2) * 16;
    const int y  = blockIdx.y;
    const int b  = blockIdx.z;
    const int tid = threadIdx.x;

    // ---- inline BN1 params (layer 2 only) ----
    if (!layer1) {
        if (tid < 64) {
            const int is32 = detect_is32((const unsigned short*)wdt);
            int c = tid;
            float s = 0.f, ss = 0.f;
            #pragma unroll
            for (int cp = 0; cp < 8; ++cp) {
                s  += statPrev[cp * 128 + c];
                ss += statPrev[cp * 128 + 64 + c];
            }
            float mean = s * (1.f / (float)NPC);
            float var  = fmaxf(ss * (1.f / (float)NPC) - mean * mean, 0.f);
            float inv  = rsqrtf(var + 1e-5f);
            float g = load_in(gamma, c, is32) * inv;
            scL[c] = g;
            shL[c] = load_in(beta, c, is32) - mean * g;
        }
        __syncthreads();
    }

    // ---- stage patch: rows y-1..y+1, cols x0-1..x0+16, 64 ch bf16 ----
    for (int e = tid; e < 864; e += 256) {
        int c4 = e & 15;             // 4-channel group
        int q  = e >> 4;             // 0..53 = row*18 + xo
        int xo = q % 18, row = q / 18;
        int yy = y + row - 1, xx = x0 + xo - 1;
        uint2 v = {0u, 0u};
        if (yy >= 0 && yy < 96 && xx >= 0 && xx < 96) {
            v = *(const uint2*)&in[((b * 96 + yy) * 96 + xx) * 64 + c4 * 4];
            if (!layer1) {
                int c = c4 * 4;
                float f0 = lo16(v.x) * scL[c]     + shL[c];
                float f1 = hi16(v.x) * scL[c + 1] + shL[c + 1];
                float f2 = lo16(v.y) * scL[c + 2] + shL[c + 2];
                float f3 = hi16(v.y) * scL[c + 3] + shL[c + 3];
                v.x = pk2bf(f0, f1);
                v.y = pk2bf(f2, f3);
            }
        }
        *(uint2*)&patchH[q * XSTR + c4 * 4] = v;
    }
    __syncthreads();      // patch ready; also fences scL reads before xbuf reuse

    const int lane  = tid & 63;
    const int wv    = tid >> 6;      // wave 0..3
    const int o2w   = wv >> 1;       // which o of the pair
    const int g     = wv & 1;        // i-group (MFMA K-slice)
    const int pos16 = lane & 15;     // output position (MFMA B col)
    const int quad  = lane >> 4;

    // ================= Phase 1: full own-chain priors into registers ========
    // P[k][h][r] = prior(own chain, m = 4h + r)  — 8 m per lane, no partner.
    f32x4v P[9][2];
    {
        const int o = opair * 2 + o2w;
        #pragma unroll
        for (int k = 0; k < 9; ++k) {
            const int dy = k / 3, dx = k % 3;
            short8v a = *(const short8v*)&patchH[(dy * 18 + dx + pos16) * XSTR + g * 32 + quad * 8];
            #pragma unroll
            for (int h = 0; h < 2; ++h) {
                short8v bf = *(const short8v*)&Bfr[((((o * 9 + k) * 2 + g) * 2 + h) * 64 + lane) * 8];
                P[k][h] = __builtin_amdgcn_mfma_f32_16x16x32_bf16(bf, a, (f32x4v){0.f, 0.f, 0.f, 0.f}, 0, 0, 0);
            }
        }
    }
    // One-time class pin (R21/R25: measured best with it).
    #pragma unroll
    for (int k = 0; k < 9; ++k) {
        asm("" : "+v"(P[k][0]));
        asm("" : "+v"(P[k][1]));
    }

    // ================= Phase 2: routing, zero-shuffle k-loop ================
    // n1 per chain: fully in-lane
    float n1o[9];
    float s2[8] = {0.f, 0.f, 0.f, 0.f, 0.f, 0.f, 0.f, 0.f};
    #pragma unroll
    for (int k = 0; k < 9; ++k) {
        n1o[k] = dotsq4(P[k][0]) + dotsq4(P[k][1]);
        #pragma unroll
        for (int r = 0; r < 4; ++r) {
            s2[r]     += P[k][0][r];
            s2[4 + r] += P[k][1][r];
        }
    }

    // om init = mean over all 72 (i,k): reduce chain-sums over 8 lanes
    float om[8];
    {
        float ac[8];
        #pragma unroll
        for (int r = 0; r < 8; ++r) {
            float t = s2[r];
            t += __shfl_xor(t, 16, 64);
            t += __shfl_xor(t, 32, 64);
            ac[r] = t;
        }
        float dummy = 0.f;
        xexchange8(xbufF, 0, o2w, pos16, g, quad, ac, dummy);
        #pragma unroll
        for (int r = 0; r < 8; ++r) om[r] = ac[r] * (1.f / 72.f);
    }
    float n2;
    {
        float t = om[0] * om[0];
        #pragma unroll
        for (int r = 1; r < 8; ++r) t = fmaf(om[r], om[r], t);
        n2 = t;
    }

    #pragma unroll
    for (int it = 0; it < 3; ++it) {
        float se = 0.f;
        float ac[8] = {0.f, 0.f, 0.f, 0.f, 0.f, 0.f, 0.f, 0.f};
        #pragma unroll
        for (int k = 0; k < 9; ++k) {
            float d = P[k][0][0] * om[0];
            d = fmaf(P[k][0][1], om[1], d);
            d = fmaf(P[k][0][2], om[2], d);
            d = fmaf(P[k][0][3], om[3], d);
            d = fmaf(P[k][1][0], om[4], d);
            d = fmaf(P[k][1][1], om[5], d);
            d = fmaf(P[k][1][2], om[6], d);
            d = fmaf(P[k][1][3], om[7], d);
            float denom = fmaxf(n1o[k] + n2 - d, 1e-8f);
            float e = __expf(d * __builtin_amdgcn_rcpf(denom));
            se += e;
            #pragma unroll
            for (int r = 0; r < 4; ++r) {
                ac[r]     = fmaf(e, P[k][0][r], ac[r]);
                ac[4 + r] = fmaf(e, P[k][1][r], ac[4 + r]);
            }
        }
        // reduce over 8 chains: xor16 + xor32 in-wave, then g-exchange
        se += __shfl_xor(se, 16, 64);
        se += __shfl_xor(se, 32, 64);
        #pragma unroll
        for (int r = 0; r < 8; ++r) {
            ac[r] += __shfl_xor(ac[r], 16, 64);
            ac[r] += __shfl_xor(ac[r], 32, 64);
        }
        xexchange8(xbufF, 1 + it, o2w, pos16, g, quad, ac, se);
        float inv = __builtin_amdgcn_rcpf(se);
        #pragma unroll
        for (int r = 0; r < 8; ++r) om[r] = ac[r] * inv;
        float t = om[0] * om[0];
        #pragma unroll
        for (int r = 1; r < 8; ++r) t = fmaf(om[r], om[r], t);
        n2 = t;
    }

    // ---- output + park f32 finals for BN stats (patch region, now dead) ----
    if (g == 0 && quad == 0) {
        const int o = opair * 2 + o2w;
        uint4 pk;
        pk.x = pk2bf(om[0], om[1]);
        pk.y = pk2bf(om[2], om[3]);
        pk.z = pk2bf(om[4], om[5]);
        pk.w = pk2bf(om[6], om[7]);
        *(uint4*)&yout[((b * 96 + y) * 96 + x0 + pos16) * 64 + o * 8] = pk;
        *(float4*)&omF[(o2w * 16 + pos16) * 8]     = make_float4(om[0], om[1], om[2], om[3]);
        *(float4*)&omF[(o2w * 16 + pos16) * 8 + 4] = make_float4(om[4], om[5], om[6], om[7]);
    }
    __syncthreads();

    // ---- BN stat partials: this block's 16 channels, sum over 16 positions ----
    if (tid < 32) {
        int c16 = tid & 15, sel = tid >> 4;
        int oo2 = c16 >> 3, m = c16 & 7;
        float v = 0.f;
        #pragma unroll
        for (int pp = 0; pp < 16; ++pp) {
            float t = omF[(oo2 * 16 + pp) * 8 + m];
            v += sel ? t * t : t;
        }
        int cp = (blockIdx.x + blockIdx.y * 3 + blockIdx.z) & 7;
        atomicAdd(&statL[cp * 128 + sel * 64 + (opair * 2 + oo2) * 8 + m], v);
    }
}

// ---------------------------------------------------------------------------
// Final: out[b][c][y][x] = x + bn2(y2); bn2 params computed inline per block.
// ---------------------------------------------------------------------------
__launch_bounds__(256)
__global__ void final_kernel(const void* __restrict__ xin,
                             const __hip_bfloat16* __restrict__ yt2,
                             const float* __restrict__ statL,
                             const void* __restrict__ gamma, const void* __restrict__ beta,
                             const void* __restrict__ w1,
                             void* __restrict__ outp) {
    __shared__ float tile[64 * 33];
    __shared__ float scL[64], shL[64];
    const int is32 = detect_is32((const unsigned short*)w1);
    if (threadIdx.x < 64) {
        int c = threadIdx.x;
        float s = 0.f, ss = 0.f;
        #pragma unroll
        for (int cp = 0; cp < 8; ++cp) {
            s  += statL[cp * 128 + c];
            ss += statL[cp * 128 + 64 + c];
        }
        float mean = s * (1.f / (float)NPC);
        float var  = fmaxf(ss * (1.f / (float)NPC) - mean * mean, 0.f);
        float inv  = rsqrtf(var + 1e-5f);
        float g = load_in(gamma, c, is32) * inv;
        scL[c] = g;
        shL[c] = load_in(beta, c, is32) - mean * g;
    }
    __syncthreads();

    int x0 = blockIdx.x * 32, y = blockIdx.y, b = blockIdx.z;
    for (int e = threadIdx.x; e < 1024; e += 256) {
        int c2 = e & 31, xl = e >> 5;
        unsigned v = *(const unsigned*)&yt2[((b * 96 + y) * 96 + x0 + xl) * 64 + c2 * 2];
        int c = c2 * 2;
        tile[c * 33 + xl]       = lo16(v) * scL[c]     + shL[c];
        tile[(c + 1) * 33 + xl] = hi16(v) * scL[c + 1] + shL[c + 1];
    }
    __syncthreads();
    for (int f = threadIdx.x; f < 2048; f += 256) {
        int xl = f & 31, c = f >> 5;
        int idx = ((b * 64 + c) * 96 + y) * 96 + x0 + xl;
        float v = load_in(xin, idx, is32) + tile[c * 33 + xl];
        if (is32) ((float*)outp)[idx] = v;
        else      ((__hip_bfloat16*)outp)[idx] = __float2bfloat16(v);
    }
}

// ---------------------------------------------------------------------------
extern "C" void kernel_launch(void* const* d_in, const int* in_sizes, int n_in,
                              void* d_out, int out_size, void* d_ws, size_t ws_size,
                              hipStream_t stream) {
    const void* x  = d_in[0];
    const void* w1 = d_in[1];
    const void* g1 = d_in[2];
    const void* b1 = d_in[3];
    const void* w2 = d_in[4];
    const void* g2 = d_in[5];
    const void* b2 = d_in[6];

    __hip_bfloat16* bufA = (__hip_bfloat16*)d_ws;   // xt / yt2 (bf16, aliased)
    __hip_bfloat16* bufB = bufA + NELEM;            // yt1 (bf16)
    __hip_bfloat16* Bfr1 = bufB + NELEM;            // 147456 bf16
    __hip_bfloat16* Bfr2 = Bfr1 + 147456;           // 147456 bf16
    float* statz = (float*)(Bfr2 + 147456);         // 2048 f32
    float* statL1 = statz;
    float* statL2 = statz + 1024;

    prep_kernel<<<721, 256, 0, stream>>>(x, w1, w2, bufA, Bfr1, Bfr2, statz);

    dim3 cgrid(24, 96, 2);   // (xtile of 16 x 4 o-pairs), rows, batch
    caps_kernel<<<cgrid, 256, 0, stream>>>(bufA, nullptr, nullptr, nullptr, w1,
                                           Bfr1, bufB, statL1, 1);
    caps_kernel<<<cgrid, 256, 0, stream>>>(bufB, statL1, g1, b1, w1,
                                           Bfr2, bufA, statL2, 0);
    final_kernel<<<dim3(3, 96, 2), 256, 0, stream>>>(x, bufA, statL2, g2, b2, w1, d_out);
}

// Round 11
// 159.137 us; speedup vs baseline: 1.1110x; 1.1110x over previous
//
#include <hip/hip_runtime.h>
#include <hip/hip_bf16.h>

#define HW 9216          // 96*96
#define NPC 18432        // per-channel element count for BN
#define NELEM 1179648    // 2*64*96*96
#define XSTR 72          // patch x stride (bf16): %8==0, 36dw = +4 banks/pos
#define PATCH_B 7776     // 3*18*72*2 bytes
#define XREC 12          // cross-wave exchange record: 12 f32 = 48 B (16B-aligned)
#define XBUF_B (4*2*16*2*XREC*4)   // 4 slots x o2 x pos x g x rec = 12288 B

typedef __attribute__((ext_vector_type(2))) float f32x2;
typedef __attribute__((ext_vector_type(4))) float f32x4v;
typedef __attribute__((ext_vector_type(8))) short short8v;   // 8 bf16 (4 VGPRs)

__device__ __forceinline__ int detect_is32(const unsigned short* __restrict__ w1u) {
    int lane = threadIdx.x & 63;
    int bad = 0;
    #pragma unroll
    for (int i = 0; i < 16; ++i) {
        unsigned short u = (unsigned short)(w1u[lane + i * 64] & 0x7FFF);
        bad |= (u >= 0x42C8);   // bf16 |v| >= 100 or NaN/Inf
    }
    return (__ballot(bad) != 0ULL) ? 1 : 0;
}

__device__ __forceinline__ float load_in(const void* p, int idx, int is32) {
    return is32 ? ((const float*)p)[idx]
                : __bfloat162float(((const __hip_bfloat16*)p)[idx]);
}

__device__ __forceinline__ float lo16(unsigned v) { return __int_as_float((int)(v << 16)); }
__device__ __forceinline__ float hi16(unsigned v) { return __int_as_float((int)(v & 0xFFFF0000u)); }
__device__ __forceinline__ float bfu(unsigned short u) { return __int_as_float((int)u << 16); }
__device__ __forceinline__ unsigned pk2bf(float a, float b) {
    __hip_bfloat162 h = __float22bfloat162_rn(float2{a, b});
    return *(unsigned*)&h;
}

__device__ __forceinline__ float dotsq4(const f32x4v a) {
    float t = a[0] * a[0];
    t = fmaf(a[1], a[1], t);
    t = fmaf(a[2], a[2], t);
    t = fmaf(a[3], a[3], t);
    return t;
}
__device__ __forceinline__ float dot4(const f32x4v a, const float om[4]) {
    float t = a[0] * om[0];
    t = fmaf(a[1], om[1], t);
    t = fmaf(a[2], om[2], t);
    t = fmaf(a[3], om[3], t);
    return t;
}

// ---------------------------------------------------------------------------
// prep: 0..575 x-transpose to bf16 [b][y][x][c]; 576..719 MFMA B-fragment
// tables; 720 zero BN-stat accumulators.
// R27: transpose passes vectorized (G13) — float4/ushort4 global reads,
// uint2 packed writes, 4 elements/thread. Weight-table block = R25 verbatim
// (heff relabel, validated).
// ---------------------------------------------------------------------------
__launch_bounds__(256)
__global__ void prep_kernel(const void* __restrict__ x,
                            const void* __restrict__ w1, const void* __restrict__ w2,
                            __hip_bfloat16* __restrict__ xt,
                            __hip_bfloat16* __restrict__ Bfr1,
                            __hip_bfloat16* __restrict__ Bfr2,
                            float* __restrict__ statz) {
    __shared__ float tile[64 * 33];
    const int bid = blockIdx.x;
    if (bid < 576) {
        const int is32 = detect_is32((const unsigned short*)w1);
        int xb = bid % 3, y = (bid / 3) % 96, b = bid / 288;
        int x0 = xb * 32;
        for (int e = threadIdx.x; e < 512; e += 256) {
            int xl4 = (e & 7) * 4, c = e >> 3;
            int base = ((b * 64 + c) * 96 + y) * 96 + x0 + xl4;
            float4 v;
            if (is32) {
                v = *(const float4*)&((const float*)x)[base];
            } else {
                ushort4 u = *(const ushort4*)&((const unsigned short*)x)[base];
                v = make_float4(bfu(u.x), bfu(u.y), bfu(u.z), bfu(u.w));
            }
            tile[c * 33 + xl4 + 0] = v.x;
            tile[c * 33 + xl4 + 1] = v.y;
            tile[c * 33 + xl4 + 2] = v.z;
            tile[c * 33 + xl4 + 3] = v.w;
        }
        __syncthreads();
        for (int f = threadIdx.x; f < 512; f += 256) {
            int c4 = f & 15, xl = f >> 4;
            float a0 = tile[(4 * c4 + 0) * 33 + xl];
            float a1 = tile[(4 * c4 + 1) * 33 + xl];
            float a2 = tile[(4 * c4 + 2) * 33 + xl];
            float a3 = tile[(4 * c4 + 3) * 33 + xl];
            uint2 w;
            w.x = pk2bf(a0, a1);
            w.y = pk2bf(a2, a3);
            *(uint2*)&xt[((b * 96 + y) * 96 + x0 + xl) * 64 + c4 * 4] = w;
        }
    } else if (bid < 720) {
        const int is32 = detect_is32((const unsigned short*)w1);
        int t = (bid - 576) * 256 + threadIdx.x;   // 0..36863
        int layer = t / 18432;
        int r = t - layer * 18432;
        int lane = r & 63;
        int fi = r >> 6;                 // 0..287 = ((o*9+k)*2+g)*2+h
        int h = fi & 1, g = (fi >> 1) & 1;
        int kq = fi >> 2;
        int k = kq % 9, o = kq / 9;
        int dy = k / 3, dx = k % 3;
        int quad = lane >> 4, colhi = (lane >> 3) & 1, m = lane & 7;
        int heff = h ^ (m >> 2);         // own-first relabel (validated R24/R25)
        int act = (quad == 2 * heff + colhi);
        int i = g * 4 + 2 * heff + colhi;
        const void* w = layer ? w2 : w1;
        __hip_bfloat16* dst = layer ? Bfr2 : Bfr1;
        #pragma unroll
        for (int j = 0; j < 8; ++j) {
            float v = act ? load_in(w, ((((o * 8 + i) * 3 + dy) * 3 + dx) * 8 + j) * 8 + m, is32)
                          : 0.f;
            dst[(fi * 64 + lane) * 8 + j] = __float2bfloat16(v);
        }
    } else {
        for (int e = threadIdx.x; e < 2048; e += 256) statz[e] = 0.f;
    }
}

// cross-wave (g) exchange of [4]-float partial + se through a 48B LDS record.
// quads 2,3 hold identical post-xor32 values as 0,1, so only quads 0,1 write.
__device__ __forceinline__ void xexchange(float* __restrict__ xbufF, int slot,
                                          int o2w, int pos16, int g, int quad,
                                          int mhalf, float ac[4], float& se) {
    float* rec = xbufF + ((((slot * 2 + o2w) * 16 + pos16) * 2 + g) * XREC);
    if (quad < 2) {
        *(float4*)(rec + quad * 4) = make_float4(ac[0], ac[1], ac[2], ac[3]);
        if (quad == 0) rec[8] = se;
    }
    __syncthreads();
    const float* prec = xbufF + ((((slot * 2 + o2w) * 16 + pos16) * 2 + (1 - g)) * XREC);
    float4 po = *(const float4*)(prec + mhalf * 4);
    ac[0] += po.x; ac[1] += po.y; ac[2] += po.z; ac[3] += po.w;
    se += prec[8];
}

// ---------------------------------------------------------------------------
// Fused capsule conv (MFMA) + routing + BN-stat partials.  (R27 caps = R25
// verbatim — measured best 52.6us/dispatch.)
// R26 post-mortem: full-chain remap (zero-shuffle k-loop) REGRESSED to
// 60.8us: clumping all DS shuffles into the iteration tail while waves are
// barrier-locked killed the DS||VALU overlap the interleaved R25 loop gets
// for free. Lesson: balance pipe usage temporally under barrier lockstep.
// Block = 256 threads = 4 waves; tile = 16 x-positions x TWO o.
// Wave wv = (o2w = wv>>1, g = wv&1); lane quad = (ihl = q>>1, mhalf = q&1).
// Phase 1: operand-swapped MFMA, D kept in regs (P[k][0]=own chain,
//   P[k][1]=partner chain via heff relabel).
// Phase 2: routing on P. Unit (pos,o) = 4 quads x 2 g-waves.
//   m-combine = shfl_xor16, ihl-combine = shfl_xor32, g-combine = 48B LDS
//   exchange + barrier (4 total). 9 exp-chains per lane, zero duplication.
// ---------------------------------------------------------------------------
__launch_bounds__(256, 4)
__global__ void caps_kernel(const __hip_bfloat16* __restrict__ in,  // [b][y][x][64] bf16
                            const float* __restrict__ statPrev,     // BN1 raw stats (layer2)
                            const void* __restrict__ gamma, const void* __restrict__ beta,
                            const void* __restrict__ wdt,           // w1, dtype probe
                            const __hip_bfloat16* __restrict__ Bfr,
                            __hip_bfloat16* __restrict__ yout,      // [b][y][x][64] bf16
                            float* __restrict__ statL,              // [8 copies][128]
                            int layer1) {
    __shared__ __align__(16) unsigned char smem[PATCH_B + XBUF_B];
    __hip_bfloat16* patchH = (__hip_bfloat16*)smem;       // [q=row*18+xo][c] stride XSTR
    float* xbufF = (float*)(smem + PATCH_B);              // exchange slots
    float* omF = (float*)smem;                // 1 KB, aliases patch (dead in epilogue)
    float* scL = (float*)(smem + PATCH_B);    // 256 B, aliases xbuf (staging only)
    float* shL = scL + 64;

    const int gx    = blockIdx.x;    // 0..23
    const int opair = gx & 3;
    const int x0    = (gx >> 2) * 16;
    const int y  = blockIdx.y;
    const int b  = blockIdx.z;
    const int tid = threadIdx.x;

    // ---- inline BN1 params (layer 2 only) ----
    if (!layer1) {
        if (tid < 64) {
            const int is32 = detect_is32((const unsigned short*)wdt);
            int c = tid;
            float s = 0.f, ss = 0.f;
            #pragma unroll
            for (int cp = 0; cp < 8; ++cp) {
                s  += statPrev[cp * 128 + c];
                ss += statPrev[cp * 128 + 64 + c];
            }
            float mean = s * (1.f / (float)NPC);
            float var  = fmaxf(ss * (1.f / (float)NPC) - mean * mean, 0.f);
            float inv  = rsqrtf(var + 1e-5f);
            float g = load_in(gamma, c, is32) * inv;
            scL[c] = g;
            shL[c] = load_in(beta, c, is32) - mean * g;
        }
        __syncthreads();
    }

    // ---- stage patch: rows y-1..y+1, cols x0-1..x0+16, 64 ch bf16 ----
    for (int e = tid; e < 864; e += 256) {
        int c4 = e & 15;             // 4-channel group
        int q  = e >> 4;             // 0..53 = row*18 + xo
        int xo = q % 18, row = q / 18;
        int yy = y + row - 1, xx = x0 + xo - 1;
        uint2 v = {0u, 0u};
        if (yy >= 0 && yy < 96 && xx >= 0 && xx < 96) {
            v = *(const uint2*)&in[((b * 96 + yy) * 96 + xx) * 64 + c4 * 4];
            if (!layer1) {
                int c = c4 * 4;
                float f0 = lo16(v.x) * scL[c]     + shL[c];
                float f1 = hi16(v.x) * scL[c + 1] + shL[c + 1];
                float f2 = lo16(v.y) * scL[c + 2] + shL[c + 2];
                float f3 = hi16(v.y) * scL[c + 3] + shL[c + 3];
                v.x = pk2bf(f0, f1);
                v.y = pk2bf(f2, f3);
            }
        }
        *(uint2*)&patchH[q * XSTR + c4 * 4] = v;
    }
    __syncthreads();      // patch ready; also fences scL reads before xbuf reuse

    const int lane  = tid & 63;
    const int wv    = tid >> 6;      // wave 0..3
    const int o2w   = wv >> 1;       // which o of the pair
    const int g     = wv & 1;        // i-group (MFMA K-slice)
    const int pos16 = lane & 15;     // output position (MFMA B col)
    const int quad  = lane >> 4;
    const int mhalf = quad & 1;      // m-half: m = mhalf*4 + r

    // ================= Phase 1: priors straight into registers ==============
    f32x4v P[9][2];                  // [k][0]=own chain, [1]=partner (heff)
    {
        const int o = opair * 2 + o2w;
        #pragma unroll
        for (int k = 0; k < 9; ++k) {
            const int dy = k / 3, dx = k % 3;
            short8v a = *(const short8v*)&patchH[(dy * 18 + dx + pos16) * XSTR + g * 32 + quad * 8];
            #pragma unroll
            for (int h = 0; h < 2; ++h) {
                short8v bf = *(const short8v*)&Bfr[((((o * 9 + k) * 2 + g) * 2 + h) * 64 + lane) * 8];
                P[k][h] = __builtin_amdgcn_mfma_f32_16x16x32_bf16(bf, a, (f32x4v){0.f, 0.f, 0.f, 0.f}, 0, 0, 0);
            }
        }
    }
    // One-time class pin (R21/R25: measured best with it).
    #pragma unroll
    for (int k = 0; k < 9; ++k) {
        asm("" : "+v"(P[k][0]));
        asm("" : "+v"(P[k][1]));
    }

    // ================= Phase 2: routing on register priors ==================
    // n1 per own chain: own-sq + partner's own-sq via xor16 (no selects)
    float n1o[9];
    #pragma unroll
    for (int k = 0; k < 9; ++k) {
        float np1 = dotsq4(P[k][1]);
        n1o[k] = dotsq4(P[k][0]) + __shfl_xor(np1, 16, 64);
    }

    // om init = mean over all 72 (i,k): in-lane (k,h) + xor32 (ihl) + g-exchange
    float om[4];
    {
        float ac[4];
        #pragma unroll
        for (int r = 0; r < 4; ++r) {
            float s = 0.f;
            #pragma unroll
            for (int k = 0; k < 9; ++k) s += P[k][0][r] + P[k][1][r];
            s += __shfl_xor(s, 32, 64);
            ac[r] = s;
        }
        float dummy = 0.f;
        xexchange(xbufF, 0, o2w, pos16, g, quad, mhalf, ac, dummy);
        #pragma unroll
        for (int r = 0; r < 4; ++r) om[r] = ac[r] * (1.f / 72.f);
    }
    float n2;
    {
        float n2p = dotsq4((f32x4v){om[0], om[1], om[2], om[3]});
        n2 = n2p + __shfl_xor(n2p, 16, 64);
    }

    #pragma unroll
    for (int it = 0; it < 3; ++it) {
        float se = 0.f;
        float ac[4] = {0.f, 0.f, 0.f, 0.f};
        #pragma unroll
        for (int k = 0; k < 9; ++k) {
            float dp0 = dot4(P[k][0], om);
            float dp1 = dot4(P[k][1], om);
            float d = dp0 + __shfl_xor(dp1, 16, 64);
            float denom = fmaxf(n1o[k] + n2 - d, 1e-8f);
            float e = __expf(d * __builtin_amdgcn_rcpf(denom));
            se += e;
            float eo = __shfl_xor(e, 16, 64);
            ac[0] = fmaf(e, P[k][0][0], fmaf(eo, P[k][1][0], ac[0]));
            ac[1] = fmaf(e, P[k][0][1], fmaf(eo, P[k][1][1], ac[1]));
            ac[2] = fmaf(e, P[k][0][2], fmaf(eo, P[k][1][2], ac[2]));
            ac[3] = fmaf(e, P[k][0][3], fmaf(eo, P[k][1][3], ac[3]));
        }
        // reduce: se over xor16+xor32, acc over xor32 (m-halves stay separate)
        se += __shfl_xor(se, 16, 64);
        se += __shfl_xor(se, 32, 64);
        #pragma unroll
        for (int r = 0; r < 4; ++r) ac[r] += __shfl_xor(ac[r], 32, 64);
        xexchange(xbufF, 1 + it, o2w, pos16, g, quad, mhalf, ac, se);
        float inv = __builtin_amdgcn_rcpf(se);
        #pragma unroll
        for (int r = 0; r < 4; ++r) om[r] = ac[r] * inv;
        float n2p = dotsq4((f32x4v){om[0], om[1], om[2], om[3]});
        n2 = n2p + __shfl_xor(n2p, 16, 64);
    }

    // ---- output + park f32 finals for BN stats (patch region, now dead) ----
    if (g == 0 && quad < 2) {
        const int o = opair * 2 + o2w;
        uint2 pk;
        pk.x = pk2bf(om[0], om[1]);
        pk.y = pk2bf(om[2], om[3]);
        *(uint2*)&yout[((b * 96 + y) * 96 + x0 + pos16) * 64 + o * 8 + mhalf * 4] = pk;
        *(float4*)&omF[(o2w * 16 + pos16) * 8 + mhalf * 4] = make_float4(om[0], om[1], om[2], om[3]);
    }
    __syncthreads();

    // ---- BN stat partials: this block's 16 channels, sum over 16 positions ----
    if (tid < 32) {
        int c16 = tid & 15, sel = tid >> 4;
        int oo2 = c16 >> 3, m = c16 & 7;
        float v = 0.f;
        #pragma unroll
        for (int pp = 0; pp < 16; ++pp) {
            float t = omF[(oo2 * 16 + pp) * 8 + m];
            v += sel ? t * t : t;
        }
        int cp = (blockIdx.x + blockIdx.y * 3 + blockIdx.z) & 7;
        atomicAdd(&statL[cp * 128 + sel * 64 + (opair * 2 + oo2) * 8 + m], v);
    }
}

// ---------------------------------------------------------------------------
// Final: out[b][c][y][x] = x + bn2(y2); bn2 params computed inline per block.
// R27: vectorized (G13) — uint2 yt2 reads, float4/ushort4 x reads, packed
// uint2/float4 output writes; 4 elements/thread.
// ---------------------------------------------------------------------------
__launch_bounds__(256)
__global__ void final_kernel(const void* __restrict__ xin,
                             const __hip_bfloat16* __restrict__ yt2,
                             const float* __restrict__ statL,
                             const void* __restrict__ gamma, const void* __restrict__ beta,
                             const void* __restrict__ w1,
                             void* __restrict__ outp) {
    __shared__ float tile[64 * 33];
    __shared__ float scL[64], shL[64];
    const int is32 = detect_is32((const unsigned short*)w1);
    if (threadIdx.x < 64) {
        int c = threadIdx.x;
        float s = 0.f, ss = 0.f;
        #pragma unroll
        for (int cp = 0; cp < 8; ++cp) {
            s  += statL[cp * 128 + c];
            ss += statL[cp * 128 + 64 + c];
        }
        float mean = s * (1.f / (float)NPC);
        float var  = fmaxf(ss * (1.f / (float)NPC) - mean * mean, 0.f);
        float inv  = rsqrtf(var + 1e-5f);
        float g = load_in(gamma, c, is32) * inv;
        scL[c] = g;
        shL[c] = load_in(beta, c, is32) - mean * g;
    }
    __syncthreads();

    int x0 = blockIdx.x * 32, y = blockIdx.y, b = blockIdx.z;
    for (int e = threadIdx.x; e < 512; e += 256) {
        int c4 = e & 15, xl = e >> 4;
        uint2 v = *(const uint2*)&yt2[((b * 96 + y) * 96 + x0 + xl) * 64 + c4 * 4];
        int c = c4 * 4;
        tile[(c + 0) * 33 + xl] = lo16(v.x) * scL[c]     + shL[c];
        tile[(c + 1) * 33 + xl] = hi16(v.x) * scL[c + 1] + shL[c + 1];
        tile[(c + 2) * 33 + xl] = lo16(v.y) * scL[c + 2] + shL[c + 2];
        tile[(c + 3) * 33 + xl] = hi16(v.y) * scL[c + 3] + shL[c + 3];
    }
    __syncthreads();
    for (int f = threadIdx.x; f < 512; f += 256) {
        int xl4 = (f & 7) * 4, c = f >> 3;
        int idx = ((b * 64 + c) * 96 + y) * 96 + x0 + xl4;
        float4 xv;
        if (is32) {
            xv = *(const float4*)&((const float*)xin)[idx];
        } else {
            ushort4 u = *(const ushort4*)&((const unsigned short*)xin)[idx];
            xv = make_float4(bfu(u.x), bfu(u.y), bfu(u.z), bfu(u.w));
        }
        float r0 = xv.x + tile[c * 33 + xl4 + 0];
        float r1 = xv.y + tile[c * 33 + xl4 + 1];
        float r2 = xv.z + tile[c * 33 + xl4 + 2];
        float r3 = xv.w + tile[c * 33 + xl4 + 3];
        if (is32) {
            *(float4*)&((float*)outp)[idx] = make_float4(r0, r1, r2, r3);
        } else {
            uint2 w;
            w.x = pk2bf(r0, r1);
            w.y = pk2bf(r2, r3);
            *(uint2*)&((__hip_bfloat16*)outp)[idx] = w;
        }
    }
}

// ---------------------------------------------------------------------------
extern "C" void kernel_launch(void* const* d_in, const int* in_sizes, int n_in,
                              void* d_out, int out_size, void* d_ws, size_t ws_size,
                              hipStream_t stream) {
    const void* x  = d_in[0];
    const void* w1 = d_in[1];
    const void* g1 = d_in[2];
    const void* b1 = d_in[3];
    const void* w2 = d_in[4];
    const void* g2 = d_in[5];
    const void* b2 = d_in[6];

    __hip_bfloat16* bufA = (__hip_bfloat16*)d_ws;   // xt / yt2 (bf16, aliased)
    __hip_bfloat16* bufB = bufA + NELEM;            // yt1 (bf16)
    __hip_bfloat16* Bfr1 = bufB + NELEM;            // 147456 bf16
    __hip_bfloat16* Bfr2 = Bfr1 + 147456;           // 147456 bf16
    float* statz = (float*)(Bfr2 + 147456);         // 2048 f32
    float* statL1 = statz;
    float* statL2 = statz + 1024;

    prep_kernel<<<721, 256, 0, stream>>>(x, w1, w2, bufA, Bfr1, Bfr2, statz);

    dim3 cgrid(24, 96, 2);   // (xtile of 16 x 4 o-pairs), rows, batch
    caps_kernel<<<cgrid, 256, 0, stream>>>(bufA, nullptr, nullptr, nullptr, w1,
                                           Bfr1, bufB, statL1, 1);
    caps_kernel<<<cgrid, 256, 0, stream>>>(bufB, statL1, g1, b1, w1,
                                           Bfr2, bufA, statL2, 0);
    final_kernel<<<dim3(3, 96, 2), 256, 0, stream>>>(x, bufA, statL2, g2, b2, w1, d_out);
}